// Round 5
// baseline (93.785 us; speedup 1.0000x reference)
//
#include <hip/hip_runtime.h>
#include <hip/hip_bf16.h>

#define HW_   262144   // 512*512
#define C_    256
#define NP_   64
#define BCOLS 128
#define NBLK_ 2048     // HW_/BCOLS
#define SENT  3.0e38f

typedef __attribute__((ext_vector_type(8))) __bf16 bf16x8;
typedef __attribute__((ext_vector_type(4))) float f32x4;

__device__ __forceinline__ void top5_insert(float (&t)[5], float v) {
  if (v < t[4]) {
    t[4] = v;
    if (t[4] < t[3]) { float x = t[3]; t[3] = t[4]; t[4] = x; }
    if (t[3] < t[2]) { float x = t[2]; t[2] = t[3]; t[3] = x; }
    if (t[2] < t[1]) { float x = t[1]; t[1] = t[2]; t[2] = x; }
    if (t[1] < t[0]) { float x = t[0]; t[0] = t[1]; t[1] = x; }
  }
}

// K1: one block per pair; thread t = channel. Emits bf16 sel [pair][chan] + fp32 norms.
__global__ void gather_sel_kernel(const float* __restrict__ f1,
                                  const void* __restrict__ pairs,
                                  unsigned short* __restrict__ selb,  // [64][256] bf16 bits
                                  float* __restrict__ n_p) {
  __shared__ float red[256];
  __shared__ int sidx;
  const int p = blockIdx.x, t = threadIdx.x;
  if (t == 0) {
    const long long* ll = (const long long*)pairs;
    const int* ii = (const int*)pairs;
    bool is64 = true;
    for (int k = 0; k < 8; ++k) {
      long long v = ll[k];
      if (v < 0 || v >= (long long)HW_) is64 = false;
    }
    sidx = is64 ? (int)ll[2 * p] : ii[2 * p];
  }
  __syncthreads();
  const int idx = sidx;
  float v = f1[(size_t)t * HW_ + idx];
  __bf16 b = (__bf16)v;
  selb[p * 256 + t] = __builtin_bit_cast(unsigned short, b);
  red[t] = v * v;
  __syncthreads();
  for (int s = 128; s > 0; s >>= 1) {
    if (t < s) red[t] += red[t + s];
    __syncthreads();
  }
  if (t == 0) n_p[p] = red[0];
}

// K2: MFMA GEMM (64 x 262144 x 256) with reg-staged (T14) B pipeline.
// 256 threads = 4 waves; block covers 128 cols; wave w owns 32 cols.
// LDS 48KB: A (32KB, swizzled bf16) + B bf16 [32k][128c] double-buffer (2x8KB).
// 3 blocks/CU; global loads are contiguous float4 (streaming-optimal).
__global__ __launch_bounds__(256, 3) void dist_topk_kernel(
    const float* __restrict__ f2, const unsigned short* __restrict__ selb,
    const float* __restrict__ n_p, float* __restrict__ cand) {
  __shared__ __align__(16) char smemB[49152];
  float* smemF = (float*)smemB;          // epilogue d-tile view [64][128]
  const int tid = threadIdx.x;
  const int w = tid >> 6, lane = tid & 63;
  const int m_l = lane & 15, kq = lane >> 4;
  const int j0 = blockIdx.x * BCOLS;
  const int ch_row = tid >> 5;           // stage: this thread's base row mod 8
  const int ch_c4 = (tid & 31) * 4;      // stage: this thread's 4-col offset

  // ---- stage A (64x256 bf16 = 32KB) into LDS, byte ^= ((row&7)<<4) swizzle ----
  {
    const uint4* src = (const uint4*)selb;   // 2048 x 16B
#pragma unroll
    for (int i = 0; i < 8; ++i) {
      const int idx = i * 256 + tid;
      const int m = idx >> 5;                // 32 uint4 per 512B row
      unsigned off = (unsigned)(idx * 16) ^ ((m & 7) << 4);
      *(uint4*)(smemB + off) = src[idx];
    }
  }

#define STAGE_LOAD(R, T)                                                        \
  _Pragma("unroll") for (int i = 0; i < 4; ++i) {                               \
    const int row = i * 8 + ch_row;                                             \
    R[i] = *(const float4*)(f2 + (size_t)((T) * 32 + row) * HW_ + j0 + ch_c4);  \
  }
#define STAGE_WRITE(R, BUF)                                                     \
  _Pragma("unroll") for (int i = 0; i < 4; ++i) {                               \
    const int row = i * 8 + ch_row;                                             \
    ushort4 pk;                                                                 \
    pk.x = __builtin_bit_cast(unsigned short, (__bf16)R[i].x);                  \
    pk.y = __builtin_bit_cast(unsigned short, (__bf16)R[i].y);                  \
    pk.z = __builtin_bit_cast(unsigned short, (__bf16)R[i].z);                  \
    pk.w = __builtin_bit_cast(unsigned short, (__bf16)R[i].w);                  \
    *(ushort4*)(smemB + 32768 + (BUF) * 8192 + row * 256 + ch_c4 * 2) = pk;     \
  }

  // ---- prologue: tile 0 into buf 0 ----
  {
    float4 r[4];
    STAGE_LOAD(r, 0)
    STAGE_WRITE(r, 0)
  }
  __syncthreads();

  f32x4 acc[4][2];
#pragma unroll
  for (int mt = 0; mt < 4; ++mt)
#pragma unroll
    for (int nt = 0; nt < 2; ++nt) acc[mt][nt] = (f32x4){0.f, 0.f, 0.f, 0.f};
  float njp[2] = {0.f, 0.f};

#pragma unroll 1
  for (int t = 0; t < 8; ++t) {
    float4 r[4];
    if (t < 7) { STAGE_LOAD(r, t + 1) }    // issue-early: hides under compute

    // ---- compute tile t from buf (t&1) ----
    const char* Bb = smemB + 32768 + (t & 1) * 8192;
    bf16x8 afr[4];
#pragma unroll
    for (int mt = 0; mt < 4; ++mt) {
      unsigned offA =
          (unsigned)((mt * 16 + m_l) * 512 + kq * 16 + t * 64) ^ ((m_l & 7) << 4);
      afr[mt] = *(const bf16x8*)(smemB + offA);
    }
    bf16x8 bfr[2];
#pragma unroll
    for (int nt = 0; nt < 2; ++nt) {
      const int col = w * 32 + nt * 16 + m_l;
#pragma unroll
      for (int e = 0; e < 8; ++e) {
        unsigned short us =
            *(const unsigned short*)(Bb + (kq * 8 + e) * 256 + col * 2);
        bfr[nt][e] = __builtin_bit_cast(__bf16, us);
        float fv = __builtin_bit_cast(float, (unsigned)us << 16);
        njp[nt] = fmaf(fv, fv, njp[nt]);
      }
    }
#pragma unroll
    for (int mt = 0; mt < 4; ++mt)
#pragma unroll
      for (int nt = 0; nt < 2; ++nt)
        acc[mt][nt] = __builtin_amdgcn_mfma_f32_16x16x32_bf16(
            afr[mt], bfr[nt], acc[mt][nt], 0, 0, 0);

    if (t < 7) { STAGE_WRITE(r, (t + 1) & 1) }   // write-late: vmcnt waits here
    __syncthreads();
  }
#undef STAGE_LOAD
#undef STAGE_WRITE

  // ---- finalize column norms across the 4 k-groups sharing a column ----
  float njc[2];
#pragma unroll
  for (int nt = 0; nt < 2; ++nt) {
    float v = njp[nt];
    v += __shfl_xor(v, 16);
    v += __shfl_xor(v, 32);
    njc[nt] = v;
  }

  // ---- d = relu(n_p + n_j - 2*dot) -> swizzled LDS (reuse A region) ----
  // C/D frag: row(pair) = mt*16 + kq*4 + r, col = w*32 + nt*16 + m_l
#pragma unroll
  for (int mt = 0; mt < 4; ++mt) {
#pragma unroll
    for (int r = 0; r < 4; ++r) {
      const int pair = mt * 16 + kq * 4 + r;
      const float np = n_p[pair];
#pragma unroll
      for (int nt = 0; nt < 2; ++nt) {
        const int col = w * 32 + nt * 16 + m_l;
        float d = np + njc[nt] - 2.0f * acc[mt][nt][r];
        smemF[pair * 128 + (col ^ (pair & 31))] = fmaxf(d, 0.0f);
      }
    }
  }
  __syncthreads();

  // ---- per-pair top-5 over this block's 128 cols: 4 threads/pair ----
  const int pp = tid & 63, q = tid >> 6;
  float t5[5] = {SENT, SENT, SENT, SENT, SENT};
#pragma unroll 4
  for (int i = 0; i < 32; ++i) {
    const int col = q * 32 + i;
    float v = smemF[pp * 128 + (col ^ (pp & 31))];
    top5_insert(t5, v);
  }
  __syncthreads();
#pragma unroll
  for (int k = 0; k < 5; ++k) smemF[tid * 5 + k] = t5[k];
  __syncthreads();
  if (tid < 64) {
    float m5[5] = {SENT, SENT, SENT, SENT, SENT};
    for (int g = 0; g < 4; ++g)
#pragma unroll
      for (int k = 0; k < 5; ++k) top5_insert(m5, smemF[(g * 64 + tid) * 5 + k]);
    float* cc = cand + (size_t)blockIdx.x * (NP_ * 5) + tid * 5;
#pragma unroll
    for (int k = 0; k < 5; ++k) cc[k] = m5[k];
  }
}

// K3: reduce 2048 blocks' candidates -> per-pair mean of 5 smallest.
__global__ void topk_reduce_kernel(const float* __restrict__ cand,
                                   float* __restrict__ mean5) {
  __shared__ float lds[256 * 5];
  const int p = blockIdx.x, tid = threadIdx.x;
  float t5[5] = {SENT, SENT, SENT, SENT, SENT};
  for (int b = tid; b < NBLK_; b += 256) {
    const float* cc = cand + (size_t)b * (NP_ * 5) + p * 5;
#pragma unroll
    for (int k = 0; k < 5; ++k) top5_insert(t5, cc[k]);
  }
#pragma unroll
  for (int k = 0; k < 5; ++k) lds[tid * 5 + k] = t5[k];
  __syncthreads();
  float m2[5] = {SENT, SENT, SENT, SENT, SENT};
  if (tid < 32) {
    for (int t2 = tid * 8; t2 < tid * 8 + 8; ++t2)
#pragma unroll
      for (int k = 0; k < 5; ++k) top5_insert(m2, lds[t2 * 5 + k]);
  }
  __syncthreads();
  if (tid < 32) {
#pragma unroll
    for (int k = 0; k < 5; ++k) lds[tid * 5 + k] = m2[k];
  }
  __syncthreads();
  if (tid == 0) {
    float f[5] = {SENT, SENT, SENT, SENT, SENT};
    for (int t2 = 0; t2 < 32; ++t2)
#pragma unroll
      for (int k = 0; k < 5; ++k) top5_insert(f, lds[t2 * 5 + k]);
    mean5[p] = (f[0] + f[1] + f[2] + f[3] + f[4]) * 0.2f;
  }
}

// K4: final sum over pairs (deterministic).
__global__ void final_sum_kernel(const float* __restrict__ mean5,
                                 float* __restrict__ out) {
  const int tid = threadIdx.x;  // 1 wave
  float v = mean5[tid];
  for (int off = 32; off > 0; off >>= 1) v += __shfl_down(v, off);
  if (tid == 0) out[0] = v * (1.0f / 64.0f);
}

extern "C" void kernel_launch(void* const* d_in, const int* in_sizes, int n_in,
                              void* d_out, int out_size, void* d_ws, size_t ws_size,
                              hipStream_t stream) {
  const float* f1 = (const float*)d_in[0];
  const float* f2 = (const float*)d_in[1];
  const void* pairs = d_in[2];
  float* out = (float*)d_out;
  float* ws = (float*)d_ws;

  float*          n_p   = ws;                          // 64 f
  unsigned short* selb  = (unsigned short*)(ws + 64);  // 16384 ushort (32KB)
  float*          cand  = ws + 64 + 8192;              // 2048*64*5 f
  float*          mean5 = ws + 64 + 8192 + 655360;     // 64 f

  gather_sel_kernel<<<NP_, 256, 0, stream>>>(f1, pairs, selb, n_p);
  dist_topk_kernel<<<NBLK_, 256, 0, stream>>>(f2, selb, n_p, cand);
  topk_reduce_kernel<<<NP_, 256, 0, stream>>>(cand, mean5);
  final_sum_kernel<<<1, 64, 0, stream>>>(mean5, out);
}

// Round 6
// 82.773 us; speedup vs baseline: 1.1330x; 1.1330x over previous
//
#include <hip/hip_runtime.h>
#include <hip/hip_bf16.h>

#define HW_   262144   // 512*512
#define C_    256
#define NP_   64
#define NBLK_ 1024     // HW_/256 cols per block
#define SENT  3.0e38f

typedef __attribute__((ext_vector_type(8))) __bf16 bf16x8;
typedef __attribute__((ext_vector_type(4))) float f32x4;

__device__ __forceinline__ void top5_insert(float (&t)[5], float v) {
  if (v < t[4]) {
    t[4] = v;
    if (t[4] < t[3]) { float x = t[3]; t[3] = t[4]; t[4] = x; }
    if (t[3] < t[2]) { float x = t[2]; t[2] = t[3]; t[3] = x; }
    if (t[2] < t[1]) { float x = t[1]; t[1] = t[2]; t[2] = x; }
    if (t[1] < t[0]) { float x = t[0]; t[0] = t[1]; t[1] = x; }
  }
}

// K1: one block per pair; thread t = channel. Emits bf16 sel [pair][chan] + fp32 norms.
__global__ void gather_sel_kernel(const float* __restrict__ f1,
                                  const void* __restrict__ pairs,
                                  unsigned short* __restrict__ selb,  // [64][256] bf16 bits
                                  float* __restrict__ n_p) {
  __shared__ float red[256];
  __shared__ int sidx;
  const int p = blockIdx.x, t = threadIdx.x;
  if (t == 0) {
    const long long* ll = (const long long*)pairs;
    const int* ii = (const int*)pairs;
    bool is64 = true;
    for (int k = 0; k < 8; ++k) {
      long long v = ll[k];
      if (v < 0 || v >= (long long)HW_) is64 = false;
    }
    sidx = is64 ? (int)ll[2 * p] : ii[2 * p];
  }
  __syncthreads();
  const int idx = sidx;
  float v = f1[(size_t)t * HW_ + idx];
  __bf16 b = (__bf16)v;
  selb[p * 256 + t] = __builtin_bit_cast(unsigned short, b);
  red[t] = v * v;
  __syncthreads();
  for (int s = 128; s > 0; s >>= 1) {
    if (t < s) red[t] += red[t + s];
    __syncthreads();
  }
  if (t == 0) n_p[p] = red[0];
}

// K2: MFMA GEMM (64 x 262144 x 256) fused with norms + relu + per-block top-5.
// 512 threads = 8 waves; wave w owns cols [j0+32w, j0+32w+32) (2 N-tiles).
// Register TRIPLE-buffer B (depth-2 prefetch): 2x in-flight bytes vs round 4,
// zero K-loop barriers. Unsigned element offsets -> SGPR-base + voffset loads.
__global__ __launch_bounds__(512, 4) void dist_topk_kernel(
    const float* __restrict__ f2, const unsigned short* __restrict__ selb,
    const float* __restrict__ n_p, float* __restrict__ cand) {
  __shared__ float smem[64 * 256];   // 64 KB; bytes [0,32K) double as A-tile
  char* smemB = (char*)smem;
  const int tid = threadIdx.x;
  const int w = tid >> 6, lane = tid & 63;
  const int m_l = lane & 15, kq = lane >> 4;
  const int j0 = blockIdx.x * 256;

  // ---- stage A (64x256 bf16 = 32KB) into LDS, byte ^= ((row&7)<<4) swizzle ----
  {
    const uint4* src = (const uint4*)selb;            // 2048 x 16B
#pragma unroll
    for (int i = 0; i < 4; ++i) {
      const int idx = i * 512 + tid;
      const int m = idx >> 5;                          // 32 uint4 per 512B row
      unsigned off = (unsigned)(idx * 16) ^ ((m & 7) << 4);
      *(uint4*)(smemB + off) = src[idx];
    }
  }
  __syncthreads();

  // per-lane base element offset (col part); row part is compile-time uniform
  const unsigned colbase = (unsigned)(j0 + w * 32 + m_l);
  const unsigned rowbase = (unsigned)(kq * 8) * HW_;

  f32x4 acc[4][2];
#pragma unroll
  for (int mt = 0; mt < 4; ++mt)
#pragma unroll
    for (int nt = 0; nt < 2; ++nt) acc[mt][nt] = (f32x4){0.f, 0.f, 0.f, 0.f};
  float njp[2] = {0.f, 0.f};

  float b0[16], b1[16], b2[16];
  // element (k = kq*8+e + 32*T, col = colbase + 16*nt)
#define LOADB(BUF, T)                                                          \
  _Pragma("unroll") for (int nt = 0; nt < 2; ++nt)                             \
  _Pragma("unroll") for (int e = 0; e < 8; ++e)                                \
      BUF[nt * 8 + e] =                                                        \
          f2[rowbase + colbase + (unsigned)(((T) * 32 + e) * HW_ + nt * 16)];

  LOADB(b0, 0)
  LOADB(b1, 1)

#define STEP(CUR, NXT, T, PF)                                                   \
  {                                                                             \
    if (PF) { LOADB(NXT, (T) + 2) }                                             \
    bf16x8 afr[4];                                                              \
    _Pragma("unroll") for (int mt = 0; mt < 4; ++mt) {                          \
      unsigned offA =                                                           \
          (unsigned)((mt * 16 + m_l) * 512 + kq * 16 + (T) * 64) ^              \
          ((m_l & 7) << 4);                                                     \
      afr[mt] = *(const bf16x8*)(smemB + offA);                                 \
    }                                                                           \
    bf16x8 bfr[2];                                                              \
    _Pragma("unroll") for (int nt = 0; nt < 2; ++nt) {                          \
      _Pragma("unroll") for (int e = 0; e < 8; ++e) {                           \
        float v = CUR[nt * 8 + e];                                              \
        njp[nt] = fmaf(v, v, njp[nt]);                                          \
        bfr[nt][e] = (__bf16)v;                                                 \
      }                                                                         \
    }                                                                           \
    _Pragma("unroll") for (int mt = 0; mt < 4; ++mt)                            \
      _Pragma("unroll") for (int nt = 0; nt < 2; ++nt)                          \
        acc[mt][nt] = __builtin_amdgcn_mfma_f32_16x16x32_bf16(                  \
            afr[mt], bfr[nt], acc[mt][nt], 0, 0, 0);                            \
  }

  STEP(b0, b2, 0, 1) STEP(b1, b0, 1, 1) STEP(b2, b1, 2, 1) STEP(b0, b2, 3, 1)
  STEP(b1, b0, 4, 1) STEP(b2, b1, 5, 1) STEP(b0, b2, 6, 0) STEP(b1, b0, 7, 0)
#undef STEP
#undef LOADB

  // ---- finalize column norms across the 4 k-groups sharing a column ----
  float njc[2];
#pragma unroll
  for (int nt = 0; nt < 2; ++nt) {
    float v = njp[nt];
    v += __shfl_xor(v, 16);
    v += __shfl_xor(v, 32);
    njc[nt] = v;
  }

  __syncthreads();   // all waves done reading A; smem becomes the d-tile

  // ---- d = relu(n_p + n_j - 2*dot) -> swizzled LDS ----
  // C/D frag: row(pair) = mt*16 + kq*4 + r, col = w*32 + nt*16 + m_l
#pragma unroll
  for (int mt = 0; mt < 4; ++mt) {
#pragma unroll
    for (int r = 0; r < 4; ++r) {
      const int pair = mt * 16 + kq * 4 + r;
      const float np = n_p[pair];
#pragma unroll
      for (int nt = 0; nt < 2; ++nt) {
        const int col = w * 32 + nt * 16 + m_l;
        float d = np + njc[nt] - 2.0f * acc[mt][nt][r];
        smem[pair * 256 + (col ^ (pair & 31))] = fmaxf(d, 0.0f);
      }
    }
  }
  __syncthreads();

  // ---- per-pair top-5 over this block's 256 cols: 8 threads/pair ----
  const int pp = tid & 63, q = tid >> 6;
  float t5[5] = {SENT, SENT, SENT, SENT, SENT};
#pragma unroll 4
  for (int i = 0; i < 32; ++i) {
    const int col = q * 32 + i;
    float v = smem[pp * 256 + (col ^ (pp & 31))];
    top5_insert(t5, v);
  }
  __syncthreads();
#pragma unroll
  for (int k = 0; k < 5; ++k) smem[tid * 5 + k] = t5[k];
  __syncthreads();
  if (tid < 64) {
    float m5[5] = {SENT, SENT, SENT, SENT, SENT};
    for (int g = 0; g < 8; ++g)
#pragma unroll
      for (int k = 0; k < 5; ++k) top5_insert(m5, smem[(g * 64 + tid) * 5 + k]);
    float* cc = cand + (size_t)blockIdx.x * (NP_ * 5) + tid * 5;
#pragma unroll
    for (int k = 0; k < 5; ++k) cc[k] = m5[k];
  }
}

// K3: reduce 1024 blocks' candidates -> per-pair mean of 5 smallest.
__global__ void topk_reduce_kernel(const float* __restrict__ cand,
                                   float* __restrict__ mean5) {
  __shared__ float lds[256 * 5];
  const int p = blockIdx.x, tid = threadIdx.x;
  float t5[5] = {SENT, SENT, SENT, SENT, SENT};
  for (int b = tid; b < NBLK_; b += 256) {
    const float* cc = cand + (size_t)b * (NP_ * 5) + p * 5;
#pragma unroll
    for (int k = 0; k < 5; ++k) top5_insert(t5, cc[k]);
  }
#pragma unroll
  for (int k = 0; k < 5; ++k) lds[tid * 5 + k] = t5[k];
  __syncthreads();
  float m2[5] = {SENT, SENT, SENT, SENT, SENT};
  if (tid < 32) {
    for (int t2 = tid * 8; t2 < tid * 8 + 8; ++t2)
#pragma unroll
      for (int k = 0; k < 5; ++k) top5_insert(m2, lds[t2 * 5 + k]);
  }
  __syncthreads();
  if (tid < 32) {
#pragma unroll
    for (int k = 0; k < 5; ++k) lds[tid * 5 + k] = m2[k];
  }
  __syncthreads();
  if (tid == 0) {
    float f[5] = {SENT, SENT, SENT, SENT, SENT};
    for (int t2 = 0; t2 < 32; ++t2)
#pragma unroll
      for (int k = 0; k < 5; ++k) top5_insert(f, lds[t2 * 5 + k]);
    mean5[p] = (f[0] + f[1] + f[2] + f[3] + f[4]) * 0.2f;
  }
}

// K4: final sum over pairs (deterministic).
__global__ void final_sum_kernel(const float* __restrict__ mean5,
                                 float* __restrict__ out) {
  const int tid = threadIdx.x;  // 1 wave
  float v = mean5[tid];
  for (int off = 32; off > 0; off >>= 1) v += __shfl_down(v, off);
  if (tid == 0) out[0] = v * (1.0f / 64.0f);
}

extern "C" void kernel_launch(void* const* d_in, const int* in_sizes, int n_in,
                              void* d_out, int out_size, void* d_ws, size_t ws_size,
                              hipStream_t stream) {
  const float* f1 = (const float*)d_in[0];
  const float* f2 = (const float*)d_in[1];
  const void* pairs = d_in[2];
  float* out = (float*)d_out;
  float* ws = (float*)d_ws;

  float*          n_p   = ws;                         // 64 f
  unsigned short* selb  = (unsigned short*)(ws + 64); // 16384 ushort (32KB)
  float*          cand  = ws + 64 + 8192;             // 1024*64*5 f
  float*          mean5 = ws + 64 + 8192 + 327680;    // 64 f

  gather_sel_kernel<<<NP_, 256, 0, stream>>>(f1, pairs, selb, n_p);
  dist_topk_kernel<<<NBLK_, 512, 0, stream>>>(f2, selb, n_p, cand);
  topk_reduce_kernel<<<NP_, 256, 0, stream>>>(cand, mean5);
  final_sum_kernel<<<1, 64, 0, stream>>>(mean5, out);
}